// Round 9
// baseline (209.466 us; speedup 1.0000x reference)
//
#include <hip/hip_runtime.h>
#include <hip/hip_bf16.h>

// GCN layer. Algebra: A2[n] = A1[n].*x[n], so only A1 (+cnt) is edge-accumulated.
//   out[n] = LeakyReLU(A1@W1^T + (A1.*x[n])@W2^T + c*(b1+b2), 0.2)
//
// Pipeline (4 kernels, R17 == R16 resubmit; R16 died on "container failed
// twice" = infra flake signature identical to R2, whose resubmit passed.
// Audit found no fault/hang path: scans guarded, barriers uniform, Phase B
// loop terminates, workspace smaller than accepted R11 layout):
//   1. prep_init: bf16 node table + gcur[b*32] = b*BCAP (128B-padded cursors)
//   2. part_scatter: LDS bin-sort by bucket (dst>>7). R16: 20-barrier ladder
//      scan -> hierarchical wave-shfl scan (4 barriers); gcur cursors padded
//      to 1/cacheline (was 32 bins/line x 391 blocks x 8 XCDs false sharing).
//   3. accum_fused: one block per 128-node bucket. Phase A: hist/scan/
//      scatter into LDS srt[2304] (scan single-wave shfl, 2 barriers).
//      Phase B (R16): TWO LOCS PER WAVE concurrently -- fused staging loop,
//      4 dwordx4 gathers in flight/iter (was 2). R15 counters: VALU 40%,
//      HBM 34%, neither saturated => latency*MLP-bound; 13.5 waves/CU x 2
//      gathers = 2.4 TB/s model matched measured 2.3. Pairing doubles MLP;
//      ~35% zero-FMA imbalance waste absorbed by idle VALU.
//      R13/R14 LESSON stands: LDS FP atomics ~236cyc/instr un-pipelined --
//      never stream through them; INT hist atomics fine.
//   4. node_gemm (R10): MFMA 16x16x32 bf16, out = Acat @ Wcat^T.
//
// Record: uint2{ src, (dst<<15) | q15(norm) }  (dst<131072 fits 17 bits)
// ws (4B units): cnt[N] | gcur[NB*32] | epk[NB*BCAP*2] | xbf[N*32]
// xbf packing: word w of node n = bf16(x[w+32])<<16 | bf16(x[w])
// Acat packing (64 u32 words/row, k-permuted): lane sl (0..7) owns
//   words 4sl..4sl+3   = pk(a1[4sl],a1[4sl+1]) pk(a1[4sl+2],a1[4sl+3])
//                        pk(a1[4sl+32],..33)   pk(a1[4sl+34],..35)
//   words 32+4sl..+3   = same with a2 = a1.*xd
// Wcat LDS mirrors this k-order; word j<32 from W1, j>=32 from W2.

#define CHUNK 4096
#define NBMAX 1024
#define BCAP  2304   // per-128-node-bucket capacity: mean 2046, sigma 45 -> +5.7σ
#define GSTR  32     // gcur cacheline stride (128 B)

typedef __attribute__((ext_vector_type(8))) short short8v;   // 8 bf16
typedef __attribute__((ext_vector_type(4))) float f32x4;
union U4S8 { uint4 u; short8v s; };

__device__ __forceinline__ unsigned int f2bf(float f) {
    unsigned int u = __float_as_uint(f);
    u += 0x7fffu + ((u >> 16) & 1u);
    return u >> 16;
}
__device__ __forceinline__ unsigned int pkbf(float lo, float hi) {
    return (f2bf(hi) << 16) | f2bf(lo);
}

__global__ __launch_bounds__(256) void prep_init_kernel(
    const float* __restrict__ srcEmb, const float* __restrict__ dstEmb,
    unsigned int* __restrict__ xbf, int* __restrict__ gcur,
    int Ntot, int n_src, int NB)
{
    int i = blockIdx.x * 256 + threadIdx.x;
    if (i < NB) gcur[i * GSTR] = i * BCAP;
    if (i >= Ntot * 32) return;
    int n = i >> 5, w = i & 31;
    const float* row = (n < n_src) ? srcEmb + (size_t)n * 64
                                   : dstEmb + (size_t)(n - n_src) * 64;
    xbf[i] = (f2bf(row[w + 32]) << 16) | f2bf(row[w]);
}

// 1024 threads, 4096 edges/block (4 per thread, held in registers).
__global__ __launch_bounds__(1024) void part_scatter_kernel(
    const int* __restrict__ es, const int* __restrict__ ed,
    const float* __restrict__ norm, int* __restrict__ gcur,
    uint2* __restrict__ epk, int E, int NB)
{
    __shared__ int   bcnt[NBMAX];    // counts -> local cursors
    __shared__ int   lstart[NBMAX];  // local run starts
    __shared__ int   gbase[NBMAX];   // reserved global run bases
    __shared__ int   wsum2[16], wbase2[16];
    __shared__ uint2 sorted[CHUNK];  // 32 KB

    int t    = threadIdx.x;
    int lane = t & 63;
    int wid  = t >> 6;
    int e0   = blockIdx.x * CHUNK;

    bcnt[t] = 0;
    __syncthreads();

    // pass 1: histogram by bucket; dst held in registers for pass 2
    int dreg[4];
    #pragma unroll
    for (int k = 0; k < 4; ++k) {
        int e = e0 + t + k * 1024;
        dreg[k] = (e < E) ? ed[e] : -1;
        if (dreg[k] >= 0) atomicAdd(&bcnt[dreg[k] >> 7], 1);
    }
    __syncthreads();

    // hierarchical scan (wave shfl + 16-wave combine): 1024 bins, 4 barriers
    int c = (t < NB) ? bcnt[t] : 0;
    int v = c;
    #pragma unroll
    for (int off = 1; off < 64; off <<= 1) {
        int x = __shfl_up(v, off);
        if (lane >= off) v += x;
    }
    if (lane == 63) wsum2[wid] = v;
    __syncthreads();
    if (t < 64) {
        int s = (t < 16) ? wsum2[t] : 0;
        #pragma unroll
        for (int off = 1; off < 16; off <<= 1) {
            int x = __shfl_up(s, off);
            if (t >= off) s += x;
        }
        if (t < 16) wbase2[t] = s - wsum2[t];
    }
    __syncthreads();
    int ex = (v - c) + wbase2[wid];
    lstart[t] = ex;
    bcnt[t]   = ex;                 // becomes local cursor
    if (c > 0) gbase[t] = atomicAdd(&gcur[t * GSTR], c);
    __syncthreads();

    // pass 2: place records into LDS sorted-by-bucket order
    #pragma unroll
    for (int k = 0; k < 4; ++k) {
        int e = e0 + t + k * 1024;
        if (dreg[k] >= 0) {
            unsigned int q = (unsigned int)(norm[e] * 32767.f + 0.5f);
            if (q > 32767u) q = 32767u;
            int lp = atomicAdd(&bcnt[dreg[k] >> 7], 1);
            uint2 r; r.x = (unsigned int)es[e];
            r.y = ((unsigned int)dreg[k] << 15) | q;
            sorted[lp] = r;
        }
    }
    __syncthreads();

    // pass 3: coalesced run dump
    int total = E - e0; if (total > CHUNK) total = CHUNK;
    for (int i = t; i < total; i += 1024) {
        uint2 r = sorted[i];
        int b = (int)(r.y >> 22);                 // dst >> 7
        int gpos = gbase[b] + (i - lstart[b]);
        if (gpos < (b + 1) * BCAP)                // overflow guard
            epk[gpos] = r;
    }
}

// R16: one block (512 thr, 8 waves) per 128-node bucket.
// Phase A: hist (INT atomics) -> single-wave shfl scan -> scatter into srt.
// Phase B: wave wv handles loc pairs (wv+16li, wv+16li+8), li=0..7.
//   Fused staging: 4 dwordx4 gathers in flight per inner iteration.
__global__ __launch_bounds__(512) void accum_fused_kernel(
    const unsigned int* __restrict__ xbf,
    const int* __restrict__ gcur, const uint2* __restrict__ epk,
    unsigned int* __restrict__ Acat, float* __restrict__ cnt, int Ntot)
{
    __shared__ uint2 srt[BCAP];     // 18.4 KB sorted records
    __shared__ int   bh[128];
    __shared__ int   offs[129];

    int b = blockIdx.x, t = threadIdx.x;
    int base  = b * BCAP;
    int total = gcur[b * GSTR] - base;
    if (total > BCAP) total = BCAP;

    // -------- Phase A: sort-by-loc into LDS --------
    if (t < 128) bh[t] = 0;
    __syncthreads();
    for (int i = t; i < total; i += 512)
        atomicAdd(&bh[(epk[base + i].y >> 15) & 127], 1);   // INT atomics: fast
    __syncthreads();

    if (t < 64) {                   // single-wave scan of 128 bins (2/lane)
        int c0 = bh[2 * t], c1 = bh[2 * t + 1];
        int p  = c0 + c1;
        #pragma unroll
        for (int off = 1; off < 64; off <<= 1) {
            int x = __shfl_up(p, off);
            if (t >= off) p += x;
        }
        int exp2_ = p - (c0 + c1);  // exclusive pair prefix
        offs[2 * t]     = exp2_;
        offs[2 * t + 1] = exp2_ + c0;
        bh[2 * t]       = exp2_;    // running cursors
        bh[2 * t + 1]   = exp2_ + c0;
        if (t == 63) offs[128] = p;
    }
    __syncthreads();

    for (int i = t; i < total; i += 512) {
        uint2 r = epk[base + i];    // L2-hot (18 KB window, 2nd pass)
        int pos = atomicAdd(&bh[(r.y >> 15) & 127], 1);
        srt[pos] = r;
    }
    __syncthreads();

    // -------- Phase B: two locs per wave, register accumulation --------
    int lane = t & 63;
    int wv   = t >> 6;
    int sl   = lane & 7;
    int g    = lane >> 3;

    for (int li = 0; li < 8; ++li) {
        int locA = wv + li * 16;
        int locB = locA + 8;
        int nA = b * 128 + locA;
        int nB = b * 128 + locB;
        int pa = offs[locA], ea = offs[locA + 1];
        int pb = offs[locB], eb = offs[locB + 1];

        float Aax0=0.f,Aax1=0.f,Aax2=0.f,Aax3=0.f;
        float Aay0=0.f,Aay1=0.f,Aay2=0.f,Aay3=0.f;
        float Bax0=0.f,Bax1=0.f,Bax2=0.f,Bax3=0.f;
        float Bay0=0.f,Bay1=0.f,Bay2=0.f,Bay3=0.f;
        float cA = 0.f, cB = 0.f;

        while (pa < ea || pb < eb) {
            int mA = ea - pa; mA = mA < 0 ? 0 : (mA > 64 ? 64 : mA);
            int mB = eb - pb; mB = mB < 0 ? 0 : (mB > 64 ? 64 : mB);
            unsigned int pax=0u, pay=0u, pbx=0u, pby=0u;   // 0 => w=0
            if (lane < mA) { uint2 r = srt[pa + lane]; pax = r.x; pay = r.y; }
            if (lane < mB) { uint2 r = srt[pb + lane]; pbx = r.x; pby = r.y; }
            int mm = mA > mB ? mA : mB;
            for (int k = 0; k < mm; k += 16) {
                unsigned int sxa0 = __shfl(pax, k + g);
                unsigned int sya0 = __shfl(pay, k + g);
                unsigned int sxa1 = __shfl(pax, k + 8 + g);
                unsigned int sya1 = __shfl(pay, k + 8 + g);
                unsigned int sxb0 = __shfl(pbx, k + g);
                unsigned int syb0 = __shfl(pby, k + g);
                unsigned int sxb1 = __shfl(pbx, k + 8 + g);
                unsigned int syb1 = __shfl(pby, k + 8 + g);
                uint4 ua0 = *(const uint4*)(xbf + (size_t)sxa0 * 32 + 4 * sl);
                uint4 ua1 = *(const uint4*)(xbf + (size_t)sxa1 * 32 + 4 * sl);
                uint4 ub0 = *(const uint4*)(xbf + (size_t)sxb0 * 32 + 4 * sl);
                uint4 ub1 = *(const uint4*)(xbf + (size_t)sxb1 * 32 + 4 * sl);
                float wa0 = (float)(sya0 & 0x7fffu) * (1.f / 32767.f);
                float wa1 = (float)(sya1 & 0x7fffu) * (1.f / 32767.f);
                float wb0 = (float)(syb0 & 0x7fffu) * (1.f / 32767.f);
                float wb1 = (float)(syb1 & 0x7fffu) * (1.f / 32767.f);
                Aax0 = fmaf(wa0, __uint_as_float(ua0.x << 16), Aax0);
                Aax1 = fmaf(wa0, __uint_as_float(ua0.y << 16), Aax1);
                Aax2 = fmaf(wa0, __uint_as_float(ua0.z << 16), Aax2);
                Aax3 = fmaf(wa0, __uint_as_float(ua0.w << 16), Aax3);
                Aay0 = fmaf(wa0, __uint_as_float(ua0.x & 0xffff0000u), Aay0);
                Aay1 = fmaf(wa0, __uint_as_float(ua0.y & 0xffff0000u), Aay1);
                Aay2 = fmaf(wa0, __uint_as_float(ua0.z & 0xffff0000u), Aay2);
                Aay3 = fmaf(wa0, __uint_as_float(ua0.w & 0xffff0000u), Aay3);
                Aax0 = fmaf(wa1, __uint_as_float(ua1.x << 16), Aax0);
                Aax1 = fmaf(wa1, __uint_as_float(ua1.y << 16), Aax1);
                Aax2 = fmaf(wa1, __uint_as_float(ua1.z << 16), Aax2);
                Aax3 = fmaf(wa1, __uint_as_float(ua1.w << 16), Aax3);
                Aay0 = fmaf(wa1, __uint_as_float(ua1.x & 0xffff0000u), Aay0);
                Aay1 = fmaf(wa1, __uint_as_float(ua1.y & 0xffff0000u), Aay1);
                Aay2 = fmaf(wa1, __uint_as_float(ua1.z & 0xffff0000u), Aay2);
                Aay3 = fmaf(wa1, __uint_as_float(ua1.w & 0xffff0000u), Aay3);
                cA += wa0 + wa1;
                Bax0 = fmaf(wb0, __uint_as_float(ub0.x << 16), Bax0);
                Bax1 = fmaf(wb0, __uint_as_float(ub0.y << 16), Bax1);
                Bax2 = fmaf(wb0, __uint_as_float(ub0.z << 16), Bax2);
                Bax3 = fmaf(wb0, __uint_as_float(ub0.w << 16), Bax3);
                Bay0 = fmaf(wb0, __uint_as_float(ub0.x & 0xffff0000u), Bay0);
                Bay1 = fmaf(wb0, __uint_as_float(ub0.y & 0xffff0000u), Bay1);
                Bay2 = fmaf(wb0, __uint_as_float(ub0.z & 0xffff0000u), Bay2);
                Bay3 = fmaf(wb0, __uint_as_float(ub0.w & 0xffff0000u), Bay3);
                Bax0 = fmaf(wb1, __uint_as_float(ub1.x << 16), Bax0);
                Bax1 = fmaf(wb1, __uint_as_float(ub1.y << 16), Bax1);
                Bax2 = fmaf(wb1, __uint_as_float(ub1.z << 16), Bax2);
                Bax3 = fmaf(wb1, __uint_as_float(ub1.w << 16), Bax3);
                Bay0 = fmaf(wb1, __uint_as_float(ub1.x & 0xffff0000u), Bay0);
                Bay1 = fmaf(wb1, __uint_as_float(ub1.y & 0xffff0000u), Bay1);
                Bay2 = fmaf(wb1, __uint_as_float(ub1.z & 0xffff0000u), Bay2);
                Bay3 = fmaf(wb1, __uint_as_float(ub1.w & 0xffff0000u), Bay3);
                cB += wb0 + wb1;
            }
            pa += 64; pb += 64;
        }

        // reduce across the 8 record-groups (lane bits 3,4,5), both locs
        #pragma unroll
        for (int off = 8; off < 64; off <<= 1) {
            Aax0 += __shfl_xor(Aax0, off); Aax1 += __shfl_xor(Aax1, off);
            Aax2 += __shfl_xor(Aax2, off); Aax3 += __shfl_xor(Aax3, off);
            Aay0 += __shfl_xor(Aay0, off); Aay1 += __shfl_xor(Aay1, off);
            Aay2 += __shfl_xor(Aay2, off); Aay3 += __shfl_xor(Aay3, off);
            cA   += __shfl_xor(cA,   off);
            Bax0 += __shfl_xor(Bax0, off); Bax1 += __shfl_xor(Bax1, off);
            Bax2 += __shfl_xor(Bax2, off); Bax3 += __shfl_xor(Bax3, off);
            Bay0 += __shfl_xor(Bay0, off); Bay1 += __shfl_xor(Bay1, off);
            Bay2 += __shfl_xor(Bay2, off); Bay3 += __shfl_xor(Bay3, off);
            cB   += __shfl_xor(cB,   off);
        }

        if (g == 0 && nA < Ntot) {
            uint4 xv = *(const uint4*)(xbf + (size_t)nA * 32 + 4 * sl);
            float xl0 = __uint_as_float(xv.x << 16);
            float xl1 = __uint_as_float(xv.y << 16);
            float xl2 = __uint_as_float(xv.z << 16);
            float xl3 = __uint_as_float(xv.w << 16);
            float xh0 = __uint_as_float(xv.x & 0xffff0000u);
            float xh1 = __uint_as_float(xv.y & 0xffff0000u);
            float xh2 = __uint_as_float(xv.z & 0xffff0000u);
            float xh3 = __uint_as_float(xv.w & 0xffff0000u);
            uint4 w0;
            w0.x = pkbf(Aax0, Aax1); w0.y = pkbf(Aax2, Aax3);
            w0.z = pkbf(Aay0, Aay1); w0.w = pkbf(Aay2, Aay3);
            uint4 w1;
            w1.x = pkbf(Aax0 * xl0, Aax1 * xl1);
            w1.y = pkbf(Aax2 * xl2, Aax3 * xl3);
            w1.z = pkbf(Aay0 * xh0, Aay1 * xh1);
            w1.w = pkbf(Aay2 * xh2, Aay3 * xh3);
            *(uint4*)(Acat + (size_t)nA * 64 + 4 * sl)      = w0;
            *(uint4*)(Acat + (size_t)nA * 64 + 32 + 4 * sl) = w1;
            if (sl == 0) cnt[nA] = cA;
        }
        if (g == 0 && nB < Ntot) {
            uint4 xv = *(const uint4*)(xbf + (size_t)nB * 32 + 4 * sl);
            float xl0 = __uint_as_float(xv.x << 16);
            float xl1 = __uint_as_float(xv.y << 16);
            float xl2 = __uint_as_float(xv.z << 16);
            float xl3 = __uint_as_float(xv.w << 16);
            float xh0 = __uint_as_float(xv.x & 0xffff0000u);
            float xh1 = __uint_as_float(xv.y & 0xffff0000u);
            float xh2 = __uint_as_float(xv.z & 0xffff0000u);
            float xh3 = __uint_as_float(xv.w & 0xffff0000u);
            uint4 w0;
            w0.x = pkbf(Bax0, Bax1); w0.y = pkbf(Bax2, Bax3);
            w0.z = pkbf(Bay0, Bay1); w0.w = pkbf(Bay2, Bay3);
            uint4 w1;
            w1.x = pkbf(Bax0 * xl0, Bax1 * xl1);
            w1.y = pkbf(Bax2 * xl2, Bax3 * xl3);
            w1.z = pkbf(Bay0 * xh0, Bay1 * xh1);
            w1.w = pkbf(Bay2 * xh2, Bay3 * xh3);
            *(uint4*)(Acat + (size_t)nB * 64 + 4 * sl)      = w0;
            *(uint4*)(Acat + (size_t)nB * 64 + 32 + 4 * sl) = w1;
            if (sl == 0) cnt[nB] = cB;
        }
    }
}

// MFMA gemm: 64 rows/block (4 waves x 16), out = Acat @ Wcat^T + cnt*(b1+b2),
// LeakyReLU. Wcat LDS built with the same k-permutation as Acat packing.
// In-place over d_out: each wave reads only its own 16 rows before writing.
__global__ __launch_bounds__(256) void node_gemm_kernel(
    const unsigned int* __restrict__ Acat, const float* __restrict__ cnt,
    const float* __restrict__ W1, const float* __restrict__ b1,
    const float* __restrict__ W2, const float* __restrict__ b2,
    float* __restrict__ out, int Ntot)
{
    __shared__ unsigned int wlds[64 * 68];   // [o][68 words], 272B row = 17x16B

    int t     = threadIdx.x;
    int lane  = t & 63;
    int wv    = t >> 6;
    int base  = blockIdx.x * 64;
    int row16 = lane & 15;    // A-row within 16-tile / D-col within 16-tile
    int q     = lane >> 4;    // k-block 0..3

    // A-frags: 4 x 16B global loads per lane (clamped rows; guarded on store)
    int arow = base + wv * 16 + row16;
    if (arow >= Ntot) arow = Ntot - 1;
    const uint4* ap = (const uint4*)(Acat + (size_t)arow * 64);
    uint4 af[4];
    #pragma unroll
    for (int s = 0; s < 4; ++s) af[s] = ap[s * 4 + q];

    // Build Wcat LDS (bf16-pair words, k-order mirrors Acat lane packing)
    for (int i = t; i < 64 * 64; i += 256) {
        int o = i >> 6, j = i & 63;
        int jj = j & 31, sl = jj >> 2, tt = jj & 3;
        int d0 = 4 * sl + ((tt & 1) << 1) + ((tt & 2) ? 32 : 0);
        const float* wsrc = (j < 32) ? W1 : W2;
        wlds[o * 68 + j] = pkbf(wsrc[o * 64 + d0], wsrc[o * 64 + d0 + 1]);
    }

    // acc init: cnt[row]*(b1[col]+b2[col]) (fp32-exact bias path)
    float cload[4];
    #pragma unroll
    for (int r = 0; r < 4; ++r) {
        int grow = base + wv * 16 + q * 4 + r;
        cload[r] = cnt[grow < Ntot ? grow : (Ntot - 1)];
    }
    f32x4 acc[4];
    #pragma unroll
    for (int j = 0; j < 4; ++j) {
        int col = j * 16 + row16;
        float bs = b1[col] + b2[col];
        #pragma unroll
        for (int r = 0; r < 4; ++r) acc[j][r] = cload[r] * bs;
    }
    __syncthreads();

    #pragma unroll
    for (int s = 0; s < 4; ++s) {
        U4S8 a; a.u = af[s];
        #pragma unroll
        for (int j = 0; j < 4; ++j) {
            int o = j * 16 + row16;
            U4S8 bb; bb.u = *(const uint4*)(wlds + o * 68 + s * 16 + q * 4);
            acc[j] = __builtin_amdgcn_mfma_f32_16x16x32_bf16(
                a.s, bb.s, acc[j], 0, 0, 0);
        }
    }

    // epilogue: D row=(lane>>4)*4+r, col=j*16+(lane&15)
    #pragma unroll
    for (int r = 0; r < 4; ++r) {
        int grow = base + wv * 16 + q * 4 + r;
        if (grow < Ntot) {
            #pragma unroll
            for (int j = 0; j < 4; ++j) {
                float a = acc[j][r];
                out[(size_t)grow * 64 + j * 16 + row16] = (a > 0.f) ? a : 0.2f * a;
            }
        }
    }
}

extern "C" void kernel_launch(void* const* d_in, const int* in_sizes, int n_in,
                              void* d_out, int out_size, void* d_ws, size_t ws_size,
                              hipStream_t stream) {
    const float* srcEmb = (const float*)d_in[0];
    const float* dstEmb = (const float*)d_in[1];
    const float* norm   = (const float*)d_in[2];
    const float* W1     = (const float*)d_in[3];
    const float* b1     = (const float*)d_in[4];
    const float* W2     = (const float*)d_in[5];
    const float* b2     = (const float*)d_in[6];
    const int*   es     = (const int*)d_in[7];
    const int*   ed     = (const int*)d_in[8];

    const int n_src = in_sizes[0] / 64;
    const int n_dst = in_sizes[1] / 64;
    const int Ntot  = n_src + n_dst;
    const int E     = in_sizes[7];
    const int NB    = (Ntot + 127) >> 7;     // 128-node buckets (NB <= 1024)

    // Workspace carve-up (4-byte units); epk/xbf 16B-aligned (dwordx4 gathers).
    float* cnt      = (float*)d_ws;                          // Ntot
    int*   gcur     = (int*)(cnt + Ntot);                    // NB*GSTR
    size_t off4     = (size_t)Ntot + (size_t)NB * GSTR;
    off4 = (off4 + 3) & ~(size_t)3;
    uint2* epk      = (uint2*)((float*)d_ws + off4);         // NB*BCAP uint2
    unsigned int* xbf = (unsigned int*)(epk + (size_t)NB * BCAP); // Ntot*32
    unsigned int* Acat = (unsigned int*)d_out;               // Ntot*64 words (bf16 x128)

    prep_init_kernel<<<(Ntot * 32 + 255) / 256, 256, 0, stream>>>(
        srcEmb, dstEmb, xbf, gcur, Ntot, n_src, NB);

    part_scatter_kernel<<<(E + CHUNK - 1) / CHUNK, 1024, 0, stream>>>(
        es, ed, norm, gcur, epk, E, NB);

    accum_fused_kernel<<<NB, 512, 0, stream>>>(
        xbf, gcur, epk, Acat, cnt, Ntot);

    node_gemm_kernel<<<(Ntot + 63) / 64, 256, 0, stream>>>(
        Acat, cnt, W1, b1, W2, b2, (float*)d_out, Ntot);
}

// Round 10
// 193.148 us; speedup vs baseline: 1.0845x; 1.0845x over previous
//
#include <hip/hip_runtime.h>
#include <hip/hip_bf16.h>

// GCN layer. Algebra: A2[n] = A1[n].*x[n], so only A1 (+cnt) is edge-accumulated.
//   out[n] = LeakyReLU(A1@W1^T + (A1.*x[n])@W2^T + c*(b1+b2), 0.2)
//
// Pipeline (4 kernels, R18):
//   1. prep_init: bf16 node table + gcur[b] = b*BCAP  (R15 form; R16's
//      padded-cursor + scan rewrite cost ~10us un-isolated -> reverted)
//   2. part_scatter (1024 thr, 4096 edges/block): LDS bin-sort by bucket
//      (dst>>7, NB=782 bins), ONE global atomicAdd per non-empty bucket
//      reserves a CONTIGUOUS run, runs dumped coalesced.  (R15 form)
//   3. accum_fused (R18): one 256-thr block per 64-NODE HALF-BUCKET,
//      grid 2*NB=1564. R17 lesson: gathers are concurrency-bound, not
//      HBM-bound (FETCH halved, dur flat, occupancy 27%); fat 512-thr
//      blocks starved the chip. Half-bucket blocks: srt 10.2KB (SCAP=1280
//      = mean 1023 + 8 sigma, clamped), LDS ~10.8KB -> 8-block wave cap,
//      ~6 blocks/CU from grid. Phase A: hist 64 bins (INT atomics) over
//      the bucket window filtered to this half, 1-wave shfl scan, scatter
//      into srt. Phase B: R15's PROVEN single-loc inner loop (pairing
//      refuted in R17: +16 VGPR, 0 gain). R13/R14 LESSON stands: LDS FP
//      atomics ~236cyc un-pipelined -- never stream through them.
//   4. node_gemm (R10): MFMA 16x16x32 bf16, out = Acat @ Wcat^T.
//
// Record: uint2{ src, (dst<<15) | q15(norm) }  (dst<131072 fits 17 bits)
// ws (4B units): cnt[N] | gcur[NB] | epk[NB*BCAP*2] | xbf[N*32]
// xbf packing: word w of node n = bf16(x[w+32])<<16 | bf16(x[w])
// Acat packing (64 u32 words/row, k-permuted): lane sl (0..7) owns
//   words 4sl..4sl+3   = pk(a1[4sl],a1[4sl+1]) pk(a1[4sl+2],a1[4sl+3])
//                        pk(a1[4sl+32],..33)   pk(a1[4sl+34],..35)
//   words 32+4sl..+3   = same with a2 = a1.*xd
// Wcat LDS mirrors this k-order; word j<32 from W1, j>=32 from W2.

#define CHUNK 4096
#define NBMAX 1024
#define BCAP  2304   // per-128-node-bucket capacity: mean 2046, sigma 45 -> +5.7σ
#define SCAP  1280   // per-64-node half-bucket: mean 1023, sigma ~32 -> +8σ

typedef __attribute__((ext_vector_type(8))) short short8v;   // 8 bf16
typedef __attribute__((ext_vector_type(4))) float f32x4;
union U4S8 { uint4 u; short8v s; };

__device__ __forceinline__ unsigned int f2bf(float f) {
    unsigned int u = __float_as_uint(f);
    u += 0x7fffu + ((u >> 16) & 1u);
    return u >> 16;
}
__device__ __forceinline__ unsigned int pkbf(float lo, float hi) {
    return (f2bf(hi) << 16) | f2bf(lo);
}

__global__ __launch_bounds__(256) void prep_init_kernel(
    const float* __restrict__ srcEmb, const float* __restrict__ dstEmb,
    unsigned int* __restrict__ xbf, int* __restrict__ gcur,
    int Ntot, int n_src, int NB)
{
    int i = blockIdx.x * 256 + threadIdx.x;
    if (i < NB) gcur[i] = i * BCAP;
    if (i >= Ntot * 32) return;
    int n = i >> 5, w = i & 31;
    const float* row = (n < n_src) ? srcEmb + (size_t)n * 64
                                   : dstEmb + (size_t)(n - n_src) * 64;
    xbf[i] = (f2bf(row[w + 32]) << 16) | f2bf(row[w]);
}

// 1024 threads, 4096 edges/block (4 per thread, held in registers). R15 form.
__global__ __launch_bounds__(1024) void part_scatter_kernel(
    const int* __restrict__ es, const int* __restrict__ ed,
    const float* __restrict__ norm, int* __restrict__ gcur,
    uint2* __restrict__ epk, int E, int NB)
{
    __shared__ int   bcnt[NBMAX];    // counts -> local cursors
    __shared__ int   lstart[NBMAX];  // local run starts
    __shared__ int   gbase[NBMAX];   // reserved global run bases
    __shared__ int   sc[NBMAX];
    __shared__ uint2 sorted[CHUNK];  // 32 KB

    int t  = threadIdx.x;
    int e0 = blockIdx.x * CHUNK;

    bcnt[t] = 0;
    __syncthreads();

    // pass 1: histogram by bucket; dst held in registers for pass 2
    int dreg[4];
    #pragma unroll
    for (int k = 0; k < 4; ++k) {
        int e = e0 + t + k * 1024;
        dreg[k] = (e < E) ? ed[e] : -1;
        if (dreg[k] >= 0) atomicAdd(&bcnt[dreg[k] >> 7], 1);
    }
    __syncthreads();

    // full-block scan over NBMAX bins (one bin per thread) + run reservation
    int c = (t < NB) ? bcnt[t] : 0;
    sc[t] = c;
    __syncthreads();
    for (int off = 1; off < NBMAX; off <<= 1) {
        int x = 0;
        if (t >= off) x = sc[t - off];
        __syncthreads();
        if (t >= off) sc[t] += x;
        __syncthreads();
    }
    int ex = sc[t] - c;
    lstart[t] = ex;
    bcnt[t]   = ex;                 // becomes local cursor
    if (c > 0) gbase[t] = atomicAdd(&gcur[t], c);
    __syncthreads();

    // pass 2: place records into LDS sorted-by-bucket order
    #pragma unroll
    for (int k = 0; k < 4; ++k) {
        int e = e0 + t + k * 1024;
        if (dreg[k] >= 0) {
            unsigned int q = (unsigned int)(norm[e] * 32767.f + 0.5f);
            if (q > 32767u) q = 32767u;
            int lp = atomicAdd(&bcnt[dreg[k] >> 7], 1);
            uint2 r; r.x = (unsigned int)es[e];
            r.y = ((unsigned int)dreg[k] << 15) | q;
            sorted[lp] = r;
        }
    }
    __syncthreads();

    // pass 3: coalesced run dump
    int total = E - e0; if (total > CHUNK) total = CHUNK;
    for (int i = t; i < total; i += 1024) {
        uint2 r = sorted[i];
        int b = (int)(r.y >> 22);                 // dst >> 7
        int gpos = gbase[b] + (i - lstart[b]);
        if (gpos < (b + 1) * BCAP)                // overflow guard
            epk[gpos] = r;
    }
}

// R18: one 256-thread block (4 waves) per 64-node half-bucket.
// b = blk>>1, h = blk&1; handles locs [h*64, h*64+64) of bucket b.
// Phase A: hist(64 bins, filtered) -> 1-wave scan -> scatter into srt.
// Phase B: wave wv handles locs wv + 4*li (li=0..15), R15 inner loop.
__global__ __launch_bounds__(256) void accum_fused_kernel(
    const unsigned int* __restrict__ xbf,
    const int* __restrict__ gcur, const uint2* __restrict__ epk,
    unsigned int* __restrict__ Acat, float* __restrict__ cnt, int Ntot)
{
    __shared__ uint2 srt[SCAP];     // 10.2 KB sorted records (this half)
    __shared__ int   bh[64];
    __shared__ int   offs[65];

    int blk = blockIdx.x;
    int b   = blk >> 1, h = blk & 1;
    int t   = threadIdx.x;
    int base    = b * BCAP;
    int total   = gcur[b] - base;
    if (total > BCAP) total = BCAP;
    int locbase = h << 6;

    // -------- Phase A: sort this half's records by loc into LDS --------
    if (t < 64) bh[t] = 0;
    __syncthreads();
    for (int i = t; i < total; i += 256) {
        int loc = (int)((epk[base + i].y >> 15) & 127);
        if ((loc >> 6) == h) atomicAdd(&bh[loc & 63], 1);   // INT atomics
    }
    __syncthreads();

    if (t < 64) {                   // wave-0 scan of 64 bins
        int c = bh[t];
        int p = c;
        #pragma unroll
        for (int off = 1; off < 64; off <<= 1) {
            int x = __shfl_up(p, off);
            if (t >= off) p += x;
        }
        int ex = p - c;
        if (ex > SCAP) ex = SCAP;   // overflow clamp (8-sigma guard)
        int en = p;
        if (en > SCAP) en = SCAP;
        offs[t] = ex;
        if (t == 63) offs[64] = en;
        bh[t] = ex;                 // running cursor
    }
    __syncthreads();

    for (int i = t; i < total; i += 256) {
        uint2 r = epk[base + i];    // window L2/L3-hot (2nd pass)
        int loc = (int)((r.y >> 15) & 127);
        if ((loc >> 6) == h) {
            int pos = atomicAdd(&bh[loc & 63], 1);
            if (pos < SCAP) srt[pos] = r;
        }
    }
    __syncthreads();

    // -------- Phase B: register accumulation (R15 proven loop) --------
    int lane = t & 63;
    int wv   = t >> 6;
    int sl   = lane & 7;
    int g    = lane >> 3;

    for (int li = 0; li < 16; ++li) {
        int l64 = wv + (li << 2);           // 0..63 across 4 waves x 16
        int n   = b * 128 + locbase + l64;
        int s0  = offs[l64];
        int s1  = offs[l64 + 1];

        float ax0 = 0.f, ax1 = 0.f, ax2 = 0.f, ax3 = 0.f;
        float ay0 = 0.f, ay1 = 0.f, ay2 = 0.f, ay3 = 0.f;
        float c = 0.f;

        for (int bs2 = s0; bs2 < s1; bs2 += 64) {
            int m = s1 - bs2; if (m > 64) m = 64;
            unsigned int px = 0u, py = 0u;        // 0 => w=0 (src 0 harmless)
            if (lane < m) { uint2 pk = srt[bs2 + lane]; px = pk.x; py = pk.y; }
            for (int k = 0; k < m; k += 16) {
                unsigned int sx0 = __shfl(px, k + g);
                unsigned int sy0 = __shfl(py, k + g);
                unsigned int sx1 = __shfl(px, k + 8 + g);
                unsigned int sy1 = __shfl(py, k + 8 + g);
                uint4 u0 = *(const uint4*)(xbf + (size_t)sx0 * 32 + 4 * sl);
                uint4 u1 = *(const uint4*)(xbf + (size_t)sx1 * 32 + 4 * sl);
                float w0 = (float)(sy0 & 0x7fffu) * (1.f / 32767.f);
                float w1 = (float)(sy1 & 0x7fffu) * (1.f / 32767.f);
                ax0 = fmaf(w0, __uint_as_float(u0.x << 16), ax0);
                ax1 = fmaf(w0, __uint_as_float(u0.y << 16), ax1);
                ax2 = fmaf(w0, __uint_as_float(u0.z << 16), ax2);
                ax3 = fmaf(w0, __uint_as_float(u0.w << 16), ax3);
                ay0 = fmaf(w0, __uint_as_float(u0.x & 0xffff0000u), ay0);
                ay1 = fmaf(w0, __uint_as_float(u0.y & 0xffff0000u), ay1);
                ay2 = fmaf(w0, __uint_as_float(u0.z & 0xffff0000u), ay2);
                ay3 = fmaf(w0, __uint_as_float(u0.w & 0xffff0000u), ay3);
                c += w0;
                ax0 = fmaf(w1, __uint_as_float(u1.x << 16), ax0);
                ax1 = fmaf(w1, __uint_as_float(u1.y << 16), ax1);
                ax2 = fmaf(w1, __uint_as_float(u1.z << 16), ax2);
                ax3 = fmaf(w1, __uint_as_float(u1.w << 16), ax3);
                ay0 = fmaf(w1, __uint_as_float(u1.x & 0xffff0000u), ay0);
                ay1 = fmaf(w1, __uint_as_float(u1.y & 0xffff0000u), ay1);
                ay2 = fmaf(w1, __uint_as_float(u1.z & 0xffff0000u), ay2);
                ay3 = fmaf(w1, __uint_as_float(u1.w & 0xffff0000u), ay3);
                c += w1;
            }
        }

        // reduce across the 8 record-groups (lane bits 3,4,5)
        #pragma unroll
        for (int off = 8; off < 64; off <<= 1) {
            ax0 += __shfl_xor(ax0, off); ax1 += __shfl_xor(ax1, off);
            ax2 += __shfl_xor(ax2, off); ax3 += __shfl_xor(ax3, off);
            ay0 += __shfl_xor(ay0, off); ay1 += __shfl_xor(ay1, off);
            ay2 += __shfl_xor(ay2, off); ay3 += __shfl_xor(ay3, off);
            c   += __shfl_xor(c,   off);
        }

        if (g == 0 && n < Ntot) {
            // xd for this node's own dims: word 4sl+i = (x[4sl+i], x[4sl+i+32])
            uint4 xv = *(const uint4*)(xbf + (size_t)n * 32 + 4 * sl);
            float xl0 = __uint_as_float(xv.x << 16);
            float xl1 = __uint_as_float(xv.y << 16);
            float xl2 = __uint_as_float(xv.z << 16);
            float xl3 = __uint_as_float(xv.w << 16);
            float xh0 = __uint_as_float(xv.x & 0xffff0000u);
            float xh1 = __uint_as_float(xv.y & 0xffff0000u);
            float xh2 = __uint_as_float(xv.z & 0xffff0000u);
            float xh3 = __uint_as_float(xv.w & 0xffff0000u);

            uint4 w0;
            w0.x = pkbf(ax0, ax1);
            w0.y = pkbf(ax2, ax3);
            w0.z = pkbf(ay0, ay1);
            w0.w = pkbf(ay2, ay3);
            uint4 w1;
            w1.x = pkbf(ax0 * xl0, ax1 * xl1);
            w1.y = pkbf(ax2 * xl2, ax3 * xl3);
            w1.z = pkbf(ay0 * xh0, ay1 * xh1);
            w1.w = pkbf(ay2 * xh2, ay3 * xh3);
            *(uint4*)(Acat + (size_t)n * 64 + 4 * sl)      = w0;
            *(uint4*)(Acat + (size_t)n * 64 + 32 + 4 * sl) = w1;
            if (sl == 0) cnt[n] = c;
        }
    }
}

// MFMA gemm: 64 rows/block (4 waves x 16), out = Acat @ Wcat^T + cnt*(b1+b2),
// LeakyReLU. Wcat LDS built with the same k-permutation as Acat packing.
// In-place over d_out: each wave reads only its own 16 rows before writing.
__global__ __launch_bounds__(256) void node_gemm_kernel(
    const unsigned int* __restrict__ Acat, const float* __restrict__ cnt,
    const float* __restrict__ W1, const float* __restrict__ b1,
    const float* __restrict__ W2, const float* __restrict__ b2,
    float* __restrict__ out, int Ntot)
{
    __shared__ unsigned int wlds[64 * 68];   // [o][68 words], 272B row = 17x16B

    int t     = threadIdx.x;
    int lane  = t & 63;
    int wv    = t >> 6;
    int base  = blockIdx.x * 64;
    int row16 = lane & 15;    // A-row within 16-tile / D-col within 16-tile
    int q     = lane >> 4;    // k-block 0..3

    // A-frags: 4 x 16B global loads per lane (clamped rows; guarded on store)
    int arow = base + wv * 16 + row16;
    if (arow >= Ntot) arow = Ntot - 1;
    const uint4* ap = (const uint4*)(Acat + (size_t)arow * 64);
    uint4 af[4];
    #pragma unroll
    for (int s = 0; s < 4; ++s) af[s] = ap[s * 4 + q];

    // Build Wcat LDS (bf16-pair words, k-order mirrors Acat lane packing)
    for (int i = t; i < 64 * 64; i += 256) {
        int o = i >> 6, j = i & 63;
        int jj = j & 31, sl = jj >> 2, tt = jj & 3;
        int d0 = 4 * sl + ((tt & 1) << 1) + ((tt & 2) ? 32 : 0);
        const float* wsrc = (j < 32) ? W1 : W2;
        wlds[o * 68 + j] = pkbf(wsrc[o * 64 + d0], wsrc[o * 64 + d0 + 1]);
    }

    // acc init: cnt[row]*(b1[col]+b2[col]) (fp32-exact bias path)
    float cload[4];
    #pragma unroll
    for (int r = 0; r < 4; ++r) {
        int grow = base + wv * 16 + q * 4 + r;
        cload[r] = cnt[grow < Ntot ? grow : (Ntot - 1)];
    }
    f32x4 acc[4];
    #pragma unroll
    for (int j = 0; j < 4; ++j) {
        int col = j * 16 + row16;
        float bs = b1[col] + b2[col];
        #pragma unroll
        for (int r = 0; r < 4; ++r) acc[j][r] = cload[r] * bs;
    }
    __syncthreads();

    #pragma unroll
    for (int s = 0; s < 4; ++s) {
        U4S8 a; a.u = af[s];
        #pragma unroll
        for (int j = 0; j < 4; ++j) {
            int o = j * 16 + row16;
            U4S8 bb; bb.u = *(const uint4*)(wlds + o * 68 + s * 16 + q * 4);
            acc[j] = __builtin_amdgcn_mfma_f32_16x16x32_bf16(
                a.s, bb.s, acc[j], 0, 0, 0);
        }
    }

    // epilogue: D row=(lane>>4)*4+r, col=j*16+(lane&15)
    #pragma unroll
    for (int r = 0; r < 4; ++r) {
        int grow = base + wv * 16 + q * 4 + r;
        if (grow < Ntot) {
            #pragma unroll
            for (int j = 0; j < 4; ++j) {
                float a = acc[j][r];
                out[(size_t)grow * 64 + j * 16 + row16] = (a > 0.f) ? a : 0.2f * a;
            }
        }
    }
}

extern "C" void kernel_launch(void* const* d_in, const int* in_sizes, int n_in,
                              void* d_out, int out_size, void* d_ws, size_t ws_size,
                              hipStream_t stream) {
    const float* srcEmb = (const float*)d_in[0];
    const float* dstEmb = (const float*)d_in[1];
    const float* norm   = (const float*)d_in[2];
    const float* W1     = (const float*)d_in[3];
    const float* b1     = (const float*)d_in[4];
    const float* W2     = (const float*)d_in[5];
    const float* b2     = (const float*)d_in[6];
    const int*   es     = (const int*)d_in[7];
    const int*   ed     = (const int*)d_in[8];

    const int n_src = in_sizes[0] / 64;
    const int n_dst = in_sizes[1] / 64;
    const int Ntot  = n_src + n_dst;
    const int E     = in_sizes[7];
    const int NB    = (Ntot + 127) >> 7;     // 128-node buckets (NB <= 1024)

    // Workspace carve-up (4-byte units); epk/xbf 16B-aligned (dwordx4 gathers).
    float* cnt      = (float*)d_ws;                          // Ntot
    int*   gcur     = (int*)(cnt + Ntot);                    // NB
    size_t off4     = (size_t)Ntot + NB;
    off4 = (off4 + 3) & ~(size_t)3;
    uint2* epk      = (uint2*)((float*)d_ws + off4);         // NB*BCAP uint2
    unsigned int* xbf = (unsigned int*)(epk + (size_t)NB * BCAP); // Ntot*32
    unsigned int* Acat = (unsigned int*)d_out;               // Ntot*64 words (bf16 x128)

    prep_init_kernel<<<(Ntot * 32 + 255) / 256, 256, 0, stream>>>(
        srcEmb, dstEmb, xbf, gcur, Ntot, n_src, NB);

    part_scatter_kernel<<<(E + CHUNK - 1) / CHUNK, 1024, 0, stream>>>(
        es, ed, norm, gcur, epk, E, NB);

    accum_fused_kernel<<<NB * 2, 256, 0, stream>>>(
        xbf, gcur, epk, Acat, cnt, Ntot);

    node_gemm_kernel<<<(Ntot + 63) / 64, 256, 0, stream>>>(
        Acat, cnt, W1, b1, W2, b2, (float*)d_out, Ntot);
}

// Round 11
// 193.043 us; speedup vs baseline: 1.0851x; 1.0005x over previous
//
#include <hip/hip_runtime.h>
#include <hip/hip_bf16.h>

// GCN layer. Algebra: A2[n] = A1[n].*x[n], so only A1 (+cnt) is edge-accumulated.
//   out[n] = LeakyReLU(A1@W1^T + (A1.*x[n])@W2^T + c*(b1+b2), 0.2)
//
// Pipeline (4 kernels, R19):
//   1. prep_init: bf16 node table + gcur[b] = b*BCAP  (R15 form)
//   2. part_scatter (1024 thr, 4096 edges/block): LDS bin-sort by bucket
//      (dst>>7, NB=782 bins), ONE global atomicAdd per non-empty bucket
//      reserves a CONTIGUOUS run, runs dumped coalesced.  (R15 form)
//   3. accum_fused (R19): one 256-thr block per 64-node half-bucket,
//      grid 2*NB (R18's concurrency win: occ 27->47.5%, 68.5->62.4us).
//      R19 lever: Phase A single global pass -- stream the bucket window
//      ONCE (coalesced), filter this half, COMPACT into LDS raw[] via one
//      int-cursor ds_add_rtn (bucket_sort-proven primitive, NOT the R13
//      float-CAS trap) while building the 64-bin hist; scatter pass is
//      then LDS->LDS. Deletes 37.5MB of L2/L3 re-reads (R18 FETCH 160MB,
//      2 global passes x both halves = 4 window reads/bucket).
//      Phase B: R15's proven single-loc inner loop (R17 refuted pairing).
//      R13/R14 LESSON stands: LDS FP atomics ~236cyc un-pipelined.
//   4. node_gemm (R10): MFMA 16x16x32 bf16, out = Acat @ Wcat^T.
//
// Record: uint2{ src, (dst<<15) | q15(norm) }  (dst<131072 fits 17 bits)
// ws (4B units): cnt[N] | gcur[NB] | epk[NB*BCAP*2] | xbf[N*32]
// xbf packing: word w of node n = bf16(x[w+32])<<16 | bf16(x[w])
// Acat packing (64 u32 words/row, k-permuted): lane sl (0..7) owns
//   words 4sl..4sl+3   = pk(a1[4sl],a1[4sl+1]) pk(a1[4sl+2],a1[4sl+3])
//                        pk(a1[4sl+32],..33)   pk(a1[4sl+34],..35)
//   words 32+4sl..+3   = same with a2 = a1.*xd
// Wcat LDS mirrors this k-order; word j<32 from W1, j>=32 from W2.

#define CHUNK 4096
#define NBMAX 1024
#define BCAP  2304   // per-128-node-bucket capacity: mean 2046, sigma 45 -> +5.7σ
#define SCAP  1280   // per-64-node half-bucket: mean 1023, sigma ~32 -> +8σ

typedef __attribute__((ext_vector_type(8))) short short8v;   // 8 bf16
typedef __attribute__((ext_vector_type(4))) float f32x4;
union U4S8 { uint4 u; short8v s; };

__device__ __forceinline__ unsigned int f2bf(float f) {
    unsigned int u = __float_as_uint(f);
    u += 0x7fffu + ((u >> 16) & 1u);
    return u >> 16;
}
__device__ __forceinline__ unsigned int pkbf(float lo, float hi) {
    return (f2bf(hi) << 16) | f2bf(lo);
}

__global__ __launch_bounds__(256) void prep_init_kernel(
    const float* __restrict__ srcEmb, const float* __restrict__ dstEmb,
    unsigned int* __restrict__ xbf, int* __restrict__ gcur,
    int Ntot, int n_src, int NB)
{
    int i = blockIdx.x * 256 + threadIdx.x;
    if (i < NB) gcur[i] = i * BCAP;
    if (i >= Ntot * 32) return;
    int n = i >> 5, w = i & 31;
    const float* row = (n < n_src) ? srcEmb + (size_t)n * 64
                                   : dstEmb + (size_t)(n - n_src) * 64;
    xbf[i] = (f2bf(row[w + 32]) << 16) | f2bf(row[w]);
}

// 1024 threads, 4096 edges/block (4 per thread, held in registers). R15 form.
__global__ __launch_bounds__(1024) void part_scatter_kernel(
    const int* __restrict__ es, const int* __restrict__ ed,
    const float* __restrict__ norm, int* __restrict__ gcur,
    uint2* __restrict__ epk, int E, int NB)
{
    __shared__ int   bcnt[NBMAX];    // counts -> local cursors
    __shared__ int   lstart[NBMAX];  // local run starts
    __shared__ int   gbase[NBMAX];   // reserved global run bases
    __shared__ int   sc[NBMAX];
    __shared__ uint2 sorted[CHUNK];  // 32 KB

    int t  = threadIdx.x;
    int e0 = blockIdx.x * CHUNK;

    bcnt[t] = 0;
    __syncthreads();

    // pass 1: histogram by bucket; dst held in registers for pass 2
    int dreg[4];
    #pragma unroll
    for (int k = 0; k < 4; ++k) {
        int e = e0 + t + k * 1024;
        dreg[k] = (e < E) ? ed[e] : -1;
        if (dreg[k] >= 0) atomicAdd(&bcnt[dreg[k] >> 7], 1);
    }
    __syncthreads();

    // full-block scan over NBMAX bins (one bin per thread) + run reservation
    int c = (t < NB) ? bcnt[t] : 0;
    sc[t] = c;
    __syncthreads();
    for (int off = 1; off < NBMAX; off <<= 1) {
        int x = 0;
        if (t >= off) x = sc[t - off];
        __syncthreads();
        if (t >= off) sc[t] += x;
        __syncthreads();
    }
    int ex = sc[t] - c;
    lstart[t] = ex;
    bcnt[t]   = ex;                 // becomes local cursor
    if (c > 0) gbase[t] = atomicAdd(&gcur[t], c);
    __syncthreads();

    // pass 2: place records into LDS sorted-by-bucket order
    #pragma unroll
    for (int k = 0; k < 4; ++k) {
        int e = e0 + t + k * 1024;
        if (dreg[k] >= 0) {
            unsigned int q = (unsigned int)(norm[e] * 32767.f + 0.5f);
            if (q > 32767u) q = 32767u;
            int lp = atomicAdd(&bcnt[dreg[k] >> 7], 1);
            uint2 r; r.x = (unsigned int)es[e];
            r.y = ((unsigned int)dreg[k] << 15) | q;
            sorted[lp] = r;
        }
    }
    __syncthreads();

    // pass 3: coalesced run dump
    int total = E - e0; if (total > CHUNK) total = CHUNK;
    for (int i = t; i < total; i += 1024) {
        uint2 r = sorted[i];
        int b = (int)(r.y >> 22);                 // dst >> 7
        int gpos = gbase[b] + (i - lstart[b]);
        if (gpos < (b + 1) * BCAP)                // overflow guard
            epk[gpos] = r;
    }
}

// R19: one 256-thread block (4 waves) per 64-node half-bucket.
// Phase A1: ONE coalesced global pass over the bucket window; records of
//   this half are compacted into raw[] (single int-cursor ds_add_rtn) while
//   the 64-bin hist builds. Phase A2: wave-0 shfl scan -> offsets.
// Phase A3: LDS->LDS scatter raw -> srt (sorted by loc).
// Phase B: wave wv handles locs wv + 4*li (li=0..15), R15 inner loop.
__global__ __launch_bounds__(256) void accum_fused_kernel(
    const unsigned int* __restrict__ xbf,
    const int* __restrict__ gcur, const uint2* __restrict__ epk,
    unsigned int* __restrict__ Acat, float* __restrict__ cnt, int Ntot)
{
    __shared__ uint2 raw[SCAP];     // 10.2 KB compacted (unsorted, this half)
    __shared__ uint2 srt[SCAP];     // 10.2 KB sorted by loc
    __shared__ int   bh[64];
    __shared__ int   offs[65];
    __shared__ int   ccur;

    int blk = blockIdx.x;
    int b   = blk >> 1, h = blk & 1;
    int t   = threadIdx.x;
    int base    = b * BCAP;
    int total   = gcur[b] - base;
    if (total > BCAP) total = BCAP;
    int locbase = h << 6;

    if (t < 64) bh[t] = 0;
    if (t == 0) ccur = 0;
    __syncthreads();

    // -------- Phase A1: single global pass, compact + hist --------
    for (int i = t; i < total; i += 256) {
        uint2 r = epk[base + i];
        int loc = (int)((r.y >> 15) & 127);
        if ((loc >> 6) == h) {
            atomicAdd(&bh[loc & 63], 1);          // INT LDS atomic: fast
            int pos = atomicAdd(&ccur, 1);        // ds_add_rtn_u32
            if (pos < SCAP) raw[pos] = r;
        }
    }
    __syncthreads();

    // -------- Phase A2: wave-0 scan of 64 bins --------
    if (t < 64) {
        int c = bh[t];
        int p = c;
        #pragma unroll
        for (int off = 1; off < 64; off <<= 1) {
            int x = __shfl_up(p, off);
            if (t >= off) p += x;
        }
        int ex = p - c;
        if (ex > SCAP) ex = SCAP;   // overflow clamp (8-sigma guard)
        int en = p;
        if (en > SCAP) en = SCAP;
        offs[t] = ex;
        if (t == 63) offs[64] = en;
        bh[t] = ex;                 // running cursor
    }
    __syncthreads();

    // -------- Phase A3: LDS->LDS scatter by loc --------
    int nmine = ccur; if (nmine > SCAP) nmine = SCAP;
    for (int i = t; i < nmine; i += 256) {
        uint2 r = raw[i];
        int pos = atomicAdd(&bh[(r.y >> 15) & 63], 1);
        if (pos < SCAP) srt[pos] = r;
    }
    __syncthreads();

    // -------- Phase B: register accumulation (R15 proven loop) --------
    int lane = t & 63;
    int wv   = t >> 6;
    int sl   = lane & 7;
    int g    = lane >> 3;

    for (int li = 0; li < 16; ++li) {
        int l64 = wv + (li << 2);           // 0..63 across 4 waves x 16
        int n   = b * 128 + locbase + l64;
        int s0  = offs[l64];
        int s1  = offs[l64 + 1];

        float ax0 = 0.f, ax1 = 0.f, ax2 = 0.f, ax3 = 0.f;
        float ay0 = 0.f, ay1 = 0.f, ay2 = 0.f, ay3 = 0.f;
        float c = 0.f;

        for (int bs2 = s0; bs2 < s1; bs2 += 64) {
            int m = s1 - bs2; if (m > 64) m = 64;
            unsigned int px = 0u, py = 0u;        // 0 => w=0 (src 0 harmless)
            if (lane < m) { uint2 pk = srt[bs2 + lane]; px = pk.x; py = pk.y; }
            for (int k = 0; k < m; k += 16) {
                unsigned int sx0 = __shfl(px, k + g);
                unsigned int sy0 = __shfl(py, k + g);
                unsigned int sx1 = __shfl(px, k + 8 + g);
                unsigned int sy1 = __shfl(py, k + 8 + g);
                uint4 u0 = *(const uint4*)(xbf + (size_t)sx0 * 32 + 4 * sl);
                uint4 u1 = *(const uint4*)(xbf + (size_t)sx1 * 32 + 4 * sl);
                float w0 = (float)(sy0 & 0x7fffu) * (1.f / 32767.f);
                float w1 = (float)(sy1 & 0x7fffu) * (1.f / 32767.f);
                ax0 = fmaf(w0, __uint_as_float(u0.x << 16), ax0);
                ax1 = fmaf(w0, __uint_as_float(u0.y << 16), ax1);
                ax2 = fmaf(w0, __uint_as_float(u0.z << 16), ax2);
                ax3 = fmaf(w0, __uint_as_float(u0.w << 16), ax3);
                ay0 = fmaf(w0, __uint_as_float(u0.x & 0xffff0000u), ay0);
                ay1 = fmaf(w0, __uint_as_float(u0.y & 0xffff0000u), ay1);
                ay2 = fmaf(w0, __uint_as_float(u0.z & 0xffff0000u), ay2);
                ay3 = fmaf(w0, __uint_as_float(u0.w & 0xffff0000u), ay3);
                c += w0;
                ax0 = fmaf(w1, __uint_as_float(u1.x << 16), ax0);
                ax1 = fmaf(w1, __uint_as_float(u1.y << 16), ax1);
                ax2 = fmaf(w1, __uint_as_float(u1.z << 16), ax2);
                ax3 = fmaf(w1, __uint_as_float(u1.w << 16), ax3);
                ay0 = fmaf(w1, __uint_as_float(u1.x & 0xffff0000u), ay0);
                ay1 = fmaf(w1, __uint_as_float(u1.y & 0xffff0000u), ay1);
                ay2 = fmaf(w1, __uint_as_float(u1.z & 0xffff0000u), ay2);
                ay3 = fmaf(w1, __uint_as_float(u1.w & 0xffff0000u), ay3);
                c += w1;
            }
        }

        // reduce across the 8 record-groups (lane bits 3,4,5)
        #pragma unroll
        for (int off = 8; off < 64; off <<= 1) {
            ax0 += __shfl_xor(ax0, off); ax1 += __shfl_xor(ax1, off);
            ax2 += __shfl_xor(ax2, off); ax3 += __shfl_xor(ax3, off);
            ay0 += __shfl_xor(ay0, off); ay1 += __shfl_xor(ay1, off);
            ay2 += __shfl_xor(ay2, off); ay3 += __shfl_xor(ay3, off);
            c   += __shfl_xor(c,   off);
        }

        if (g == 0 && n < Ntot) {
            // xd for this node's own dims: word 4sl+i = (x[4sl+i], x[4sl+i+32])
            uint4 xv = *(const uint4*)(xbf + (size_t)n * 32 + 4 * sl);
            float xl0 = __uint_as_float(xv.x << 16);
            float xl1 = __uint_as_float(xv.y << 16);
            float xl2 = __uint_as_float(xv.z << 16);
            float xl3 = __uint_as_float(xv.w << 16);
            float xh0 = __uint_as_float(xv.x & 0xffff0000u);
            float xh1 = __uint_as_float(xv.y & 0xffff0000u);
            float xh2 = __uint_as_float(xv.z & 0xffff0000u);
            float xh3 = __uint_as_float(xv.w & 0xffff0000u);

            uint4 w0;
            w0.x = pkbf(ax0, ax1);
            w0.y = pkbf(ax2, ax3);
            w0.z = pkbf(ay0, ay1);
            w0.w = pkbf(ay2, ay3);
            uint4 w1;
            w1.x = pkbf(ax0 * xl0, ax1 * xl1);
            w1.y = pkbf(ax2 * xl2, ax3 * xl3);
            w1.z = pkbf(ay0 * xh0, ay1 * xh1);
            w1.w = pkbf(ay2 * xh2, ay3 * xh3);
            *(uint4*)(Acat + (size_t)n * 64 + 4 * sl)      = w0;
            *(uint4*)(Acat + (size_t)n * 64 + 32 + 4 * sl) = w1;
            if (sl == 0) cnt[n] = c;
        }
    }
}

// MFMA gemm: 64 rows/block (4 waves x 16), out = Acat @ Wcat^T + cnt*(b1+b2),
// LeakyReLU. Wcat LDS built with the same k-permutation as Acat packing.
// In-place over d_out: each wave reads only its own 16 rows before writing.
__global__ __launch_bounds__(256) void node_gemm_kernel(
    const unsigned int* __restrict__ Acat, const float* __restrict__ cnt,
    const float* __restrict__ W1, const float* __restrict__ b1,
    const float* __restrict__ W2, const float* __restrict__ b2,
    float* __restrict__ out, int Ntot)
{
    __shared__ unsigned int wlds[64 * 68];   // [o][68 words], 272B row = 17x16B

    int t     = threadIdx.x;
    int lane  = t & 63;
    int wv    = t >> 6;
    int base  = blockIdx.x * 64;
    int row16 = lane & 15;    // A-row within 16-tile / D-col within 16-tile
    int q     = lane >> 4;    // k-block 0..3

    // A-frags: 4 x 16B global loads per lane (clamped rows; guarded on store)
    int arow = base + wv * 16 + row16;
    if (arow >= Ntot) arow = Ntot - 1;
    const uint4* ap = (const uint4*)(Acat + (size_t)arow * 64);
    uint4 af[4];
    #pragma unroll
    for (int s = 0; s < 4; ++s) af[s] = ap[s * 4 + q];

    // Build Wcat LDS (bf16-pair words, k-order mirrors Acat lane packing)
    for (int i = t; i < 64 * 64; i += 256) {
        int o = i >> 6, j = i & 63;
        int jj = j & 31, sl = jj >> 2, tt = jj & 3;
        int d0 = 4 * sl + ((tt & 1) << 1) + ((tt & 2) ? 32 : 0);
        const float* wsrc = (j < 32) ? W1 : W2;
        wlds[o * 68 + j] = pkbf(wsrc[o * 64 + d0], wsrc[o * 64 + d0 + 1]);
    }

    // acc init: cnt[row]*(b1[col]+b2[col]) (fp32-exact bias path)
    float cload[4];
    #pragma unroll
    for (int r = 0; r < 4; ++r) {
        int grow = base + wv * 16 + q * 4 + r;
        cload[r] = cnt[grow < Ntot ? grow : (Ntot - 1)];
    }
    f32x4 acc[4];
    #pragma unroll
    for (int j = 0; j < 4; ++j) {
        int col = j * 16 + row16;
        float bs = b1[col] + b2[col];
        #pragma unroll
        for (int r = 0; r < 4; ++r) acc[j][r] = cload[r] * bs;
    }
    __syncthreads();

    #pragma unroll
    for (int s = 0; s < 4; ++s) {
        U4S8 a; a.u = af[s];
        #pragma unroll
        for (int j = 0; j < 4; ++j) {
            int o = j * 16 + row16;
            U4S8 bb; bb.u = *(const uint4*)(wlds + o * 68 + s * 16 + q * 4);
            acc[j] = __builtin_amdgcn_mfma_f32_16x16x32_bf16(
                a.s, bb.s, acc[j], 0, 0, 0);
        }
    }

    // epilogue: D row=(lane>>4)*4+r, col=j*16+(lane&15)
    #pragma unroll
    for (int r = 0; r < 4; ++r) {
        int grow = base + wv * 16 + q * 4 + r;
        if (grow < Ntot) {
            #pragma unroll
            for (int j = 0; j < 4; ++j) {
                float a = acc[j][r];
                out[(size_t)grow * 64 + j * 16 + row16] = (a > 0.f) ? a : 0.2f * a;
            }
        }
    }
}

extern "C" void kernel_launch(void* const* d_in, const int* in_sizes, int n_in,
                              void* d_out, int out_size, void* d_ws, size_t ws_size,
                              hipStream_t stream) {
    const float* srcEmb = (const float*)d_in[0];
    const float* dstEmb = (const float*)d_in[1];
    const float* norm   = (const float*)d_in[2];
    const float* W1     = (const float*)d_in[3];
    const float* b1     = (const float*)d_in[4];
    const float* W2     = (const float*)d_in[5];
    const float* b2     = (const float*)d_in[6];
    const int*   es     = (const int*)d_in[7];
    const int*   ed     = (const int*)d_in[8];

    const int n_src = in_sizes[0] / 64;
    const int n_dst = in_sizes[1] / 64;
    const int Ntot  = n_src + n_dst;
    const int E     = in_sizes[7];
    const int NB    = (Ntot + 127) >> 7;     // 128-node buckets (NB <= 1024)

    // Workspace carve-up (4-byte units); epk/xbf 16B-aligned (dwordx4 gathers).
    float* cnt      = (float*)d_ws;                          // Ntot
    int*   gcur     = (int*)(cnt + Ntot);                    // NB
    size_t off4     = (size_t)Ntot + NB;
    off4 = (off4 + 3) & ~(size_t)3;
    uint2* epk      = (uint2*)((float*)d_ws + off4);         // NB*BCAP uint2
    unsigned int* xbf = (unsigned int*)(epk + (size_t)NB * BCAP); // Ntot*32
    unsigned int* Acat = (unsigned int*)d_out;               // Ntot*64 words (bf16 x128)

    prep_init_kernel<<<(Ntot * 32 + 255) / 256, 256, 0, stream>>>(
        srcEmb, dstEmb, xbf, gcur, Ntot, n_src, NB);

    part_scatter_kernel<<<(E + CHUNK - 1) / CHUNK, 1024, 0, stream>>>(
        es, ed, norm, gcur, epk, E, NB);

    accum_fused_kernel<<<NB * 2, 256, 0, stream>>>(
        xbf, gcur, epk, Acat, cnt, Ntot);

    node_gemm_kernel<<<(Ntot + 63) / 64, 256, 0, stream>>>(
        Acat, cnt, W1, b1, W2, b2, (float*)d_out, Ntot);
}